// Round 3
// baseline (347.715 us; speedup 1.0000x reference)
//
#include <hip/hip_runtime.h>
#include <hip/hip_bf16.h>

#define H 512
#define RNK 4
#define BATCH 16
#define TT 4096
#define MTOT (BATCH * TT)

// GEMM tiling (m97-style)
#define BM 128
#define BN 128
#define BK 64

// Scan chunking: 128 chunks x 16 batches = 2048 waves = 2 waves/SIMD
#define NCHUNK 128
#define JWARM 32

// fused GEMM LDS pad
#define LDK 72

typedef __attribute__((ext_vector_type(8))) short bf16x8;
typedef __attribute__((ext_vector_type(4))) float f32x4;

__device__ inline unsigned short f2bf(float f) {
    unsigned u = __float_as_uint(f);
    u += 0x7FFFu + ((u >> 16) & 1u);   // RNE
    return (unsigned short)(u >> 16);
}
__device__ inline float bflo(unsigned w) { return __uint_as_float(w << 16); }
__device__ inline float bfhi(unsigned w) { return __uint_as_float(w & 0xFFFF0000u); }
__device__ inline float rfl(float x) {
    return __uint_as_float(__builtin_amdgcn_readfirstlane(__float_as_uint(x)));
}

// ---------------- fused fp32 GEMM -> bf16 out, XCD-chunked swizzle ----------------
// bx[m,n] = sum_k X[m,k] * W[n,k], converting fp32->bf16 (RNE) during LDS staging.
// Grid: 2048 blocks 1-D. Swizzle: xcd = l&7, idx = l>>3, t = xcd*256 + idx;
// m_tile = t>>2, n_tile = t&3  -> the 4 n-tiles of one m-tile are adjacent within
// an XCD's chunk => X-panel (256 KB fp32) fetched ~once per XCD L2, not 4x from HBM.
__global__ __launch_bounds__(256) void gemm_fused_bt_kernel(
    const float* __restrict__ X, const float* __restrict__ W, unsigned short* __restrict__ C)
{
    __shared__ unsigned short As[BM * LDK];
    __shared__ unsigned short Bs[BN * LDK];
    const int l = blockIdx.x;
    const int t = (l & 7) * ((MTOT / BM) * (H / BN) / 8) + (l >> 3);  // bijective: 2048 % 8 == 0
    const size_t mbase = (size_t)(t >> 2) * BM;   // H/BN == 4
    const int nbase = (t & 3) * BN;

    const int tid  = threadIdx.x;
    const int lane = tid & 63;
    const int wave = tid >> 6;
    const int wm = (wave >> 1) * 64;
    const int wn = (wave & 1) * 64;
    const float* Xb = X + mbase * H;
    const float* Wb = W + (size_t)nbase * H;
    f32x4 acc[4][4];
    #pragma unroll
    for (int i = 0; i < 4; ++i)
        #pragma unroll
        for (int j = 0; j < 4; ++j)
            acc[i][j] = (f32x4){0.f, 0.f, 0.f, 0.f};
    const int r  = lane & 15;
    const int qd = lane >> 4;
    for (int k0 = 0; k0 < H; k0 += BK) {
        #pragma unroll
        for (int i = 0; i < 8; ++i) {
            int idx = tid + i * 256;
            int row = idx >> 4;
            int c4  = (idx & 15) * 4;
            float4 va = *(const float4*)(Xb + (size_t)row * H + k0 + c4);
            float4 vb = *(const float4*)(Wb + (size_t)row * H + k0 + c4);
            ushort4 wa = { f2bf(va.x), f2bf(va.y), f2bf(va.z), f2bf(va.w) };
            ushort4 wb = { f2bf(vb.x), f2bf(vb.y), f2bf(vb.z), f2bf(vb.w) };
            *(ushort4*)&As[row * LDK + c4] = wa;
            *(ushort4*)&Bs[row * LDK + c4] = wb;
        }
        __syncthreads();
        #pragma unroll
        for (int kk = 0; kk < BK; kk += 32) {
            bf16x8 af[4], bfr[4];
            #pragma unroll
            for (int i = 0; i < 4; ++i)
                af[i] = *(const bf16x8*)&As[(wm + i * 16 + r) * LDK + kk + qd * 8];
            #pragma unroll
            for (int j = 0; j < 4; ++j)
                bfr[j] = *(const bf16x8*)&Bs[(wn + j * 16 + r) * LDK + kk + qd * 8];
            #pragma unroll
            for (int i = 0; i < 4; ++i)
                #pragma unroll
                for (int j = 0; j < 4; ++j)
                    acc[i][j] = __builtin_amdgcn_mfma_f32_16x16x32_bf16(
                        af[i], bfr[j], acc[i][j], 0, 0, 0);
        }
        __syncthreads();
    }
    // C/D layout: col = lane&15, row = qd*4 + e  [verified]
    #pragma unroll
    for (int i = 0; i < 4; ++i)
        #pragma unroll
        for (int j = 0; j < 4; ++j)
            #pragma unroll
            for (int e = 0; e < 4; ++e) {
                const size_t m = mbase + wm + i * 16 + qd * 4 + e;
                const int n = nbase + wn + j * 16 + r;
                C[m * H + n] = f2bf(acc[i][j][e]);
            }
}

// ---------------- DPLR scan, bf16 input: 4-step block-batched rank-4 decomposition ----------------
// h_t = D h_{t-1} + P (Q^T h_{t-1}) + u_t  reassociated per 4-step block:
//   g_j = D g_{j-1} + u_j (diag-only, g_0 = h_base)
//   y_j = Q^T g_{j-1}                      (batched cross-lane reduce, 16 values, ONE butterfly)
//   s_j = y_j + sum_{i<j} G_{j-1-i} s_i    (G_k = Q^T D^k P, 4x4, in SGPRs)
//   e_j = D e_{j-1} + P s_j, e_0 = 0;  h_j = g_j + e_j
__global__ __launch_bounds__(64) void scan_bf_kernel(
    const unsigned short* __restrict__ bx, float* __restrict__ out,
    const float* __restrict__ a_diag, const float* __restrict__ p_vec,
    const float* __restrict__ q_vec, int nchunk, int warm_max)
{
    const int lane = threadIdx.x;
    const int c = blockIdx.x;
    const int b = blockIdx.y;
    const int L = TT / nchunk;
    const int d0 = lane * 8;

    float ak[8], g[8];
    float4 pk[8], qk[8];
    #pragma unroll
    for (int j = 0; j < 8; ++j) {
        ak[j] = a_diag[d0 + j];
        pk[j] = *(const float4*)(p_vec + (d0 + j) * RNK);
        qk[j] = *(const float4*)(q_vec + (d0 + j) * RNK);
        g[j] = 0.f;
    }

    // One-time: G_k = Q^T D^k P for k=0..2 (4x4 each), allreduced then moved to SGPRs.
    float Gx[3][4][4];
    {
        float part[3][16];
        #pragma unroll
        for (int k = 0; k < 3; ++k)
            #pragma unroll
            for (int v = 0; v < 16; ++v) part[k][v] = 0.f;
        #pragma unroll
        for (int d = 0; d < 8; ++d) {
            const float a1 = ak[d], a2 = a1 * a1;
            const float qr[4] = {qk[d].x, qk[d].y, qk[d].z, qk[d].w};
            const float pc[4] = {pk[d].x, pk[d].y, pk[d].z, pk[d].w};
            #pragma unroll
            for (int r = 0; r < 4; ++r)
                #pragma unroll
                for (int cc = 0; cc < 4; ++cc) {
                    const float qp = qr[r] * pc[cc];
                    part[0][r * 4 + cc] += qp;
                    part[1][r * 4 + cc] += qp * a1;
                    part[2][r * 4 + cc] += qp * a2;
                }
        }
        #pragma unroll
        for (int off = 32; off > 0; off >>= 1)
            #pragma unroll
            for (int k = 0; k < 3; ++k)
                #pragma unroll
                for (int v = 0; v < 16; ++v)
                    part[k][v] += __shfl_xor(part[k][v], off);
        #pragma unroll
        for (int k = 0; k < 3; ++k)
            #pragma unroll
            for (int r = 0; r < 4; ++r)
                #pragma unroll
                for (int cc = 0; cc < 4; ++cc)
                    Gx[k][r][cc] = rfl(part[k][r * 4 + cc]);   // wave-uniform -> SGPR
    }

    const int warm  = (c == 0) ? 0 : warm_max;
    const int steps = warm + L;          // multiple of 4 (L=32, warm=32)
    const int nb    = steps >> 2;
    const int tstart = c * L - warm;
    const unsigned short* src = bx + (size_t)b * TT * H + d0;
    float* dst = out + (size_t)b * TT * H + d0;

    // 4-deep ring = 1 block of u's; next block's loads issued during phase 1.
    uint4 ring[4];
    #pragma unroll
    for (int j = 0; j < 4; ++j)
        ring[j] = *(const uint4*)(src + (size_t)(tstart + j) * H);

    for (int blk = 0; blk < nb; ++blk) {
        const int i0 = blk * 4;
        float yp[4][4];
        float gs[4][8];

        // phase 1: g-chain + y-partials (no cross-lane), prefetch next block
        #pragma unroll
        for (int j = 0; j < 4; ++j) {
            float y0 = 0.f, y1 = 0.f, y2 = 0.f, y3 = 0.f;
            #pragma unroll
            for (int d = 0; d < 8; ++d) {
                y0 += qk[d].x * g[d]; y1 += qk[d].y * g[d];
                y2 += qk[d].z * g[d]; y3 += qk[d].w * g[d];
            }
            yp[j][0] = y0; yp[j][1] = y1; yp[j][2] = y2; yp[j][3] = y3;

            const uint4 cur = ring[j];
            int iload = i0 + 4 + j;
            if (iload > steps - 1) iload = steps - 1;      // clamp (wave-uniform, in-bounds)
            ring[j] = *(const uint4*)(src + (size_t)(tstart + iload) * H);

            float u[8];
            u[0] = bflo(cur.x); u[1] = bfhi(cur.x);
            u[2] = bflo(cur.y); u[3] = bfhi(cur.y);
            u[4] = bflo(cur.z); u[5] = bfhi(cur.z);
            u[6] = bflo(cur.w); u[7] = bfhi(cur.w);
            #pragma unroll
            for (int d = 0; d < 8; ++d) { g[d] = ak[d] * g[d] + u[d]; gs[j][d] = g[d]; }
        }

        // phase 2: ONE batched butterfly allreduce over 16 values (6 stages, full ILP)
        #pragma unroll
        for (int off = 32; off > 0; off >>= 1)
            #pragma unroll
            for (int j = 0; j < 4; ++j)
                #pragma unroll
                for (int r = 0; r < 4; ++r)
                    yp[j][r] += __shfl_xor(yp[j][r], off);

        // phase 3: in-block rank-4 solve (redundant across lanes; G in SGPRs)
        float sv[4][4];
        #pragma unroll
        for (int r = 0; r < 4; ++r) sv[0][r] = yp[0][r];
        #pragma unroll
        for (int r = 0; r < 4; ++r) {
            float t = yp[1][r];
            #pragma unroll
            for (int cc = 0; cc < 4; ++cc) t += Gx[0][r][cc] * sv[0][cc];
            sv[1][r] = t;
        }
        #pragma unroll
        for (int r = 0; r < 4; ++r) {
            float t = yp[2][r];
            #pragma unroll
            for (int cc = 0; cc < 4; ++cc) t += Gx[1][r][cc] * sv[0][cc];
            #pragma unroll
            for (int cc = 0; cc < 4; ++cc) t += Gx[0][r][cc] * sv[1][cc];
            sv[2][r] = t;
        }
        #pragma unroll
        for (int r = 0; r < 4; ++r) {
            float t = yp[3][r];
            #pragma unroll
            for (int cc = 0; cc < 4; ++cc) t += Gx[2][r][cc] * sv[0][cc];
            #pragma unroll
            for (int cc = 0; cc < 4; ++cc) t += Gx[1][r][cc] * sv[1][cc];
            #pragma unroll
            for (int cc = 0; cc < 4; ++cc) t += Gx[0][r][cc] * sv[2][cc];
            sv[3][r] = t;
        }

        // phase 4: reconstruction h_j = g_j + e_j; store if past warm-up
        const bool dostore = (i0 >= warm);
        float e[8];
        #pragma unroll
        for (int d = 0; d < 8; ++d) e[d] = 0.f;
        #pragma unroll
        for (int j = 0; j < 4; ++j) {
            #pragma unroll
            for (int d = 0; d < 8; ++d) {
                const float ps = pk[d].x * sv[j][0] + pk[d].y * sv[j][1]
                               + pk[d].z * sv[j][2] + pk[d].w * sv[j][3];
                e[d] = ak[d] * e[d] + ps;
            }
            if (dostore) {
                float* dd = dst + (size_t)(tstart + i0 + j) * H;
                *(float4*)dd       = (float4){gs[j][0] + e[0], gs[j][1] + e[1],
                                              gs[j][2] + e[2], gs[j][3] + e[3]};
                *(float4*)(dd + 4) = (float4){gs[j][4] + e[4], gs[j][5] + e[5],
                                              gs[j][6] + e[6], gs[j][7] + e[7]};
            }
        }
        // next block's base state: h_4 = g_4 + e_4
        #pragma unroll
        for (int d = 0; d < 8; ++d) g[d] = gs[3][d] + e[d];
    }
}

// ---------------- tier-3 fallback (verified fp32 path) ----------------
__global__ __launch_bounds__(256) void gemm_fused_kernel(
    const float* __restrict__ X, const float* __restrict__ W, float* __restrict__ bx)
{
    __shared__ unsigned short As[BM * LDK];
    __shared__ unsigned short Bs[BN * LDK];
    const int tid  = threadIdx.x;
    const int lane = tid & 63;
    const int wave = tid >> 6;
    const int wm = (wave >> 1) * 64;
    const int wn = (wave & 1) * 64;
    const size_t mbase = (size_t)blockIdx.x * BM;
    const int nbase = blockIdx.y * BN;
    const float* Xb = X + mbase * H;
    const float* Wb = W + (size_t)nbase * H;
    f32x4 acc[4][4];
    #pragma unroll
    for (int i = 0; i < 4; ++i)
        #pragma unroll
        for (int j = 0; j < 4; ++j)
            acc[i][j] = (f32x4){0.f, 0.f, 0.f, 0.f};
    const int r  = lane & 15;
    const int qd = lane >> 4;
    for (int k0 = 0; k0 < H; k0 += BK) {
        #pragma unroll
        for (int i = 0; i < 8; ++i) {
            int idx = tid + i * 256;
            int row = idx >> 4;
            int c4  = (idx & 15) * 4;
            float4 va = *(const float4*)(Xb + (size_t)row * H + k0 + c4);
            float4 vb = *(const float4*)(Wb + (size_t)row * H + k0 + c4);
            ushort4 wa = { f2bf(va.x), f2bf(va.y), f2bf(va.z), f2bf(va.w) };
            ushort4 wb = { f2bf(vb.x), f2bf(vb.y), f2bf(vb.z), f2bf(vb.w) };
            *(ushort4*)&As[row * LDK + c4] = wa;
            *(ushort4*)&Bs[row * LDK + c4] = wb;
        }
        __syncthreads();
        #pragma unroll
        for (int kk = 0; kk < BK; kk += 32) {
            bf16x8 af[4], bfr[4];
            #pragma unroll
            for (int i = 0; i < 4; ++i)
                af[i] = *(const bf16x8*)&As[(wm + i * 16 + r) * LDK + kk + qd * 8];
            #pragma unroll
            for (int j = 0; j < 4; ++j)
                bfr[j] = *(const bf16x8*)&Bs[(wn + j * 16 + r) * LDK + kk + qd * 8];
            #pragma unroll
            for (int i = 0; i < 4; ++i)
                #pragma unroll
                for (int j = 0; j < 4; ++j)
                    acc[i][j] = __builtin_amdgcn_mfma_f32_16x16x32_bf16(
                        af[i], bfr[j], acc[i][j], 0, 0, 0);
        }
        __syncthreads();
    }
    #pragma unroll
    for (int i = 0; i < 4; ++i)
        #pragma unroll
        for (int j = 0; j < 4; ++j)
            #pragma unroll
            for (int e = 0; e < 4; ++e) {
                int m = wm + i * 16 + qd * 4 + e;
                int n = wn + j * 16 + r;
                bx[(mbase + m) * H + nbase + n] = acc[i][j][e];
            }
}

__global__ __launch_bounds__(64) void scan_f32_kernel(
    const float* __restrict__ bx, float* __restrict__ out,
    const float* __restrict__ a_diag, const float* __restrict__ p_vec,
    const float* __restrict__ q_vec)
{
    const int lane = threadIdx.x;
    const int b = blockIdx.y;
    const int d0 = lane * 8;
    float ak[8], hk[8];
    float4 pk[8], qk[8];
    #pragma unroll
    for (int j = 0; j < 8; ++j) {
        ak[j] = a_diag[d0 + j];
        pk[j] = *(const float4*)(p_vec + (d0 + j) * RNK);
        qk[j] = *(const float4*)(q_vec + (d0 + j) * RNK);
        hk[j] = 0.f;
    }
    const float* src = bx + (size_t)b * TT * H + d0;
    float* dst = out + (size_t)b * TT * H + d0;
    for (int i = 0; i < TT; ++i) {
        const float* sp = src + (size_t)i * H;
        float4 va = *(const float4*)sp, vb = *(const float4*)(sp + 4);
        float u[8] = {va.x, va.y, va.z, va.w, vb.x, vb.y, vb.z, vb.w};
        float s0 = 0.f, s1 = 0.f, s2 = 0.f, s3 = 0.f;
        #pragma unroll
        for (int j = 0; j < 8; ++j) {
            s0 += qk[j].x * hk[j]; s1 += qk[j].y * hk[j];
            s2 += qk[j].z * hk[j]; s3 += qk[j].w * hk[j];
        }
        #pragma unroll
        for (int off = 32; off > 0; off >>= 1) {
            s0 += __shfl_xor(s0, off); s1 += __shfl_xor(s1, off);
            s2 += __shfl_xor(s2, off); s3 += __shfl_xor(s3, off);
        }
        #pragma unroll
        for (int j = 0; j < 8; ++j)
            hk[j] = ak[j] * hk[j] + (pk[j].x * s0 + pk[j].y * s1 + pk[j].z * s2 + pk[j].w * s3) + u[j];
        float* d = dst + (size_t)i * H;
        *(float4*)d = (float4){hk[0], hk[1], hk[2], hk[3]};
        *(float4*)(d + 4) = (float4){hk[4], hk[5], hk[6], hk[7]};
    }
}

extern "C" void kernel_launch(void* const* d_in, const int* in_sizes, int n_in,
                              void* d_out, int out_size, void* d_ws, size_t ws_size,
                              hipStream_t stream) {
    (void)in_sizes; (void)n_in; (void)out_size;
    const float* x = (const float*)d_in[0];
    const float* a = (const float*)d_in[1];
    const float* p = (const float*)d_in[2];
    const float* q = (const float*)d_in[3];
    const float* w = (const float*)d_in[4];
    float* out = (float*)d_out;

    const size_t nx    = (size_t)MTOT * H;
    const size_t bxb_b = nx * 2;                  // 67.1 MB (bf16)

    if (d_ws != nullptr && ws_size >= bxb_b) {
        // fused fp32->bf16 GEMM (convert pass eliminated), bx in ws
        unsigned short* bxbf = (unsigned short*)d_ws;
        gemm_fused_bt_kernel<<<(MTOT / BM) * (H / BN), 256, 0, stream>>>(x, w, bxbf);
        dim3 g2(NCHUNK, BATCH), b2(64);
        scan_bf_kernel<<<g2, b2, 0, stream>>>(bxbf, out, a, p, q, NCHUNK, JWARM);
    } else {
        // tier 3: fp32 fused GEMM -> d_out, in-place sequential scan (verified safe)
        dim3 g1(MTOT / BM, H / BN), b1(256);
        gemm_fused_kernel<<<g1, b1, 0, stream>>>(x, w, out);
        dim3 g2(1, BATCH), b2(64);
        scan_f32_kernel<<<g2, b2, 0, stream>>>(out, out, a, p, q);
    }
}

// Round 4
// 312.982 us; speedup vs baseline: 1.1110x; 1.1110x over previous
//
#include <hip/hip_runtime.h>
#include <hip/hip_bf16.h>

#define H 512
#define RNK 4
#define BATCH 16
#define TT 4096
#define MTOT (BATCH * TT)

// GEMM tiling (m97-style)
#define BM 128
#define BN 128
#define BK 64

// Scan chunking: 128 chunks x 16 batches = 2048 waves = 2 waves/SIMD
#define NCHUNK 128
#define JWARM 32

// LDS pad (row pitch 144 B = 16B-aligned for ds_read_b128, breaks 128B bank aliasing)
#define LDK 72

typedef __attribute__((ext_vector_type(8))) short bf16x8;
typedef __attribute__((ext_vector_type(4))) float f32x4;

__device__ inline unsigned short f2bf(float f) {
    unsigned u = __float_as_uint(f);
    u += 0x7FFFu + ((u >> 16) & 1u);   // RNE
    return (unsigned short)(u >> 16);
}
__device__ inline float bflo(unsigned w) { return __uint_as_float(w << 16); }
__device__ inline float bfhi(unsigned w) { return __uint_as_float(w & 0xFFFF0000u); }
__device__ inline float rfl(float x) {
    return __uint_as_float(__builtin_amdgcn_readfirstlane(__float_as_uint(x)));
}

// ---------------- fp32 -> bf16 convert (streaming; used for W only, 0.5 MB) ----------------
__global__ __launch_bounds__(256) void convert_kernel(
    const float* __restrict__ src, unsigned short* __restrict__ dst, int n4)
{
    int i = blockIdx.x * blockDim.x + threadIdx.x;
    const int stride = gridDim.x * blockDim.x;
    for (; i < n4; i += stride) {
        float4 v = ((const float4*)src)[i];
        ushort4 o = { f2bf(v.x), f2bf(v.y), f2bf(v.z), f2bf(v.w) };
        ((ushort4*)dst)[i] = o;
    }
}

// ---------------- GEMM: X fp32 reg-staged+converted, W bf16 async-staged ----------------
// bx[m,n] = sum_k X[m,k] * Wbf[n,k]; fp32->bf16 RNE during X staging (bit-identical
// to the standalone convert path). XCD-chunked swizzle for L2 reuse of X panels.
// Pipeline per K-tile: cvt+write As(k) | barrier (drains Wlds(k)+ds_writes) |
// loadRA(k+1) issued | MFMA(k) | barrier | issueW(k+1) (Bs single-buffer safe).
__global__ __launch_bounds__(256, 2) void gemm_x32_kernel(
    const float* __restrict__ X, const unsigned short* __restrict__ Wbf,
    unsigned short* __restrict__ C)
{
    __shared__ unsigned short As[BM * LDK];  // 18 KB, padded (reg-written)
    __shared__ unsigned short Bs[BN * BK];   // 16 KB, linear (global_load_lds lane order)
    const int l = blockIdx.x;
    const int t = (l & 7) * ((MTOT / BM) * (H / BN) / 8) + (l >> 3);  // bijective: 2048 % 8 == 0
    const size_t mbase = (size_t)(t >> 2) * BM;   // H/BN == 4
    const int nbase = (t & 3) * BN;

    const int tid  = threadIdx.x;
    const int lane = tid & 63;
    const int wave = tid >> 6;
    const int wm = (wave >> 1) * 64;
    const int wn = (wave & 1) * 64;
    const int r  = lane & 15;
    const int qd = lane >> 4;
    const float* Xb = X + mbase * H;
    const unsigned short* Wb = Wbf + (size_t)nbase * H;

    f32x4 acc[4][4];
    #pragma unroll
    for (int i = 0; i < 4; ++i)
        #pragma unroll
        for (int j = 0; j < 4; ++j)
            acc[i][j] = (f32x4){0.f, 0.f, 0.f, 0.f};

    float4 ra[8];
    auto loadRA = [&](int kt) {
        const int k0 = kt * BK;
        #pragma unroll
        for (int i = 0; i < 8; ++i) {
            const int idx = tid + i * 256;
            const int row = idx >> 4;
            const int c4  = (idx & 15) * 4;
            ra[i] = *(const float4*)(Xb + (size_t)row * H + k0 + c4);
        }
    };
    auto issueW = [&](int kt) {
        const int k0 = kt * BK;
        #pragma unroll
        for (int s = 0; s < 4; ++s) {
            const int seg = wave * 4 + s;
            const int off = seg * 1024 + lane * 16;   // byte offset in 16KB tile
            const int row = off >> 7;                 // tile row (128 B pitch)
            const int inrow = off & 127;
            const char* gb = (const char*)(Wb + (size_t)row * H + k0) + inrow;
            __builtin_amdgcn_global_load_lds(
                (const __attribute__((address_space(1))) unsigned int*)gb,
                (__attribute__((address_space(3))) unsigned int*)&Bs[seg * 512], 16, 0, 0);
        }
    };

    issueW(0);
    loadRA(0);

    const int nt = H / BK;   // 8
    for (int kt = 0; kt < nt; ++kt) {
        // convert + write As (waitcnt on ra inserted by compiler at first use)
        #pragma unroll
        for (int i = 0; i < 8; ++i) {
            const int idx = tid + i * 256;
            const int row = idx >> 4;
            const int c4  = (idx & 15) * 4;
            const float4 v = ra[i];
            ushort4 wa = { f2bf(v.x), f2bf(v.y), f2bf(v.z), f2bf(v.w) };
            *(ushort4*)&As[row * LDK + c4] = wa;
        }
        __syncthreads();                       // As writes + Bs(k) async loads complete
        if (kt + 1 < nt) loadRA(kt + 1);       // in flight across MFMA (drained at barrier 2)
        #pragma unroll
        for (int kk = 0; kk < BK; kk += 32) {
            bf16x8 af[4], bfr[4];
            #pragma unroll
            for (int i = 0; i < 4; ++i)
                af[i] = *(const bf16x8*)&As[(wm + i * 16 + r) * LDK + kk + qd * 8];
            #pragma unroll
            for (int j = 0; j < 4; ++j)
                bfr[j] = *(const bf16x8*)&Bs[(wn + j * 16 + r) * BK + kk + qd * 8];
            #pragma unroll
            for (int i = 0; i < 4; ++i)
                #pragma unroll
                for (int j = 0; j < 4; ++j)
                    acc[i][j] = __builtin_amdgcn_mfma_f32_16x16x32_bf16(
                        af[i], bfr[j], acc[i][j], 0, 0, 0);
        }
        __syncthreads();                       // LDS reads done -> safe to overwrite
        if (kt + 1 < nt) issueW(kt + 1);
    }

    // C/D layout: col = lane&15, row = qd*4 + e  [verified]
    #pragma unroll
    for (int i = 0; i < 4; ++i)
        #pragma unroll
        for (int j = 0; j < 4; ++j)
            #pragma unroll
            for (int e = 0; e < 4; ++e) {
                const size_t m = mbase + wm + i * 16 + qd * 4 + e;
                const int n = nbase + wn + j * 16 + r;
                C[m * H + n] = f2bf(acc[i][j][e]);
            }
}

// ---------------- DPLR scan, bf16 input: 4-step block-batched rank-4 decomposition ----------------
// h_t = D h_{t-1} + P (Q^T h_{t-1}) + u_t  reassociated per 4-step block:
//   g_j = D g_{j-1} + u_j (diag-only, g_0 = h_base)
//   y_j = Q^T g_{j-1}                      (batched cross-lane reduce, 16 values, ONE butterfly)
//   s_j = y_j + sum_{i<j} G_{j-1-i} s_i    (G_k = Q^T D^k P, 4x4, in SGPRs)
//   e_j = D e_{j-1} + P s_j, e_0 = 0;  h_j = g_j + e_j
__global__ __launch_bounds__(64) void scan_bf_kernel(
    const unsigned short* __restrict__ bx, float* __restrict__ out,
    const float* __restrict__ a_diag, const float* __restrict__ p_vec,
    const float* __restrict__ q_vec, int nchunk, int warm_max)
{
    const int lane = threadIdx.x;
    const int c = blockIdx.x;
    const int b = blockIdx.y;
    const int L = TT / nchunk;
    const int d0 = lane * 8;

    float ak[8], g[8];
    float4 pk[8], qk[8];
    #pragma unroll
    for (int j = 0; j < 8; ++j) {
        ak[j] = a_diag[d0 + j];
        pk[j] = *(const float4*)(p_vec + (d0 + j) * RNK);
        qk[j] = *(const float4*)(q_vec + (d0 + j) * RNK);
        g[j] = 0.f;
    }

    // One-time: G_k = Q^T D^k P for k=0..2 (4x4 each), allreduced then moved to SGPRs.
    float Gx[3][4][4];
    {
        float part[3][16];
        #pragma unroll
        for (int k = 0; k < 3; ++k)
            #pragma unroll
            for (int v = 0; v < 16; ++v) part[k][v] = 0.f;
        #pragma unroll
        for (int d = 0; d < 8; ++d) {
            const float a1 = ak[d], a2 = a1 * a1;
            const float qr[4] = {qk[d].x, qk[d].y, qk[d].z, qk[d].w};
            const float pc[4] = {pk[d].x, pk[d].y, pk[d].z, pk[d].w};
            #pragma unroll
            for (int r = 0; r < 4; ++r)
                #pragma unroll
                for (int cc = 0; cc < 4; ++cc) {
                    const float qp = qr[r] * pc[cc];
                    part[0][r * 4 + cc] += qp;
                    part[1][r * 4 + cc] += qp * a1;
                    part[2][r * 4 + cc] += qp * a2;
                }
        }
        #pragma unroll
        for (int off = 32; off > 0; off >>= 1)
            #pragma unroll
            for (int k = 0; k < 3; ++k)
                #pragma unroll
                for (int v = 0; v < 16; ++v)
                    part[k][v] += __shfl_xor(part[k][v], off);
        #pragma unroll
        for (int k = 0; k < 3; ++k)
            #pragma unroll
            for (int r = 0; r < 4; ++r)
                #pragma unroll
                for (int cc = 0; cc < 4; ++cc)
                    Gx[k][r][cc] = rfl(part[k][r * 4 + cc]);   // wave-uniform -> SGPR
    }

    const int warm  = (c == 0) ? 0 : warm_max;
    const int steps = warm + L;          // multiple of 4 (L=32, warm=32)
    const int nb    = steps >> 2;
    const int tstart = c * L - warm;
    const unsigned short* src = bx + (size_t)b * TT * H + d0;
    float* dst = out + (size_t)b * TT * H + d0;

    // 4-deep ring = 1 block of u's; next block's loads issued during phase 1.
    uint4 ring[4];
    #pragma unroll
    for (int j = 0; j < 4; ++j)
        ring[j] = *(const uint4*)(src + (size_t)(tstart + j) * H);

    for (int blk = 0; blk < nb; ++blk) {
        const int i0 = blk * 4;
        float yp[4][4];
        float gs[4][8];

        // phase 1: g-chain + y-partials (no cross-lane), prefetch next block
        #pragma unroll
        for (int j = 0; j < 4; ++j) {
            float y0 = 0.f, y1 = 0.f, y2 = 0.f, y3 = 0.f;
            #pragma unroll
            for (int d = 0; d < 8; ++d) {
                y0 += qk[d].x * g[d]; y1 += qk[d].y * g[d];
                y2 += qk[d].z * g[d]; y3 += qk[d].w * g[d];
            }
            yp[j][0] = y0; yp[j][1] = y1; yp[j][2] = y2; yp[j][3] = y3;

            const uint4 cur = ring[j];
            int iload = i0 + 4 + j;
            if (iload > steps - 1) iload = steps - 1;      // clamp (wave-uniform, in-bounds)
            ring[j] = *(const uint4*)(src + (size_t)(tstart + iload) * H);

            float u[8];
            u[0] = bflo(cur.x); u[1] = bfhi(cur.x);
            u[2] = bflo(cur.y); u[3] = bfhi(cur.y);
            u[4] = bflo(cur.z); u[5] = bfhi(cur.z);
            u[6] = bflo(cur.w); u[7] = bfhi(cur.w);
            #pragma unroll
            for (int d = 0; d < 8; ++d) { g[d] = ak[d] * g[d] + u[d]; gs[j][d] = g[d]; }
        }

        // phase 2: ONE batched butterfly allreduce over 16 values (6 stages, full ILP)
        #pragma unroll
        for (int off = 32; off > 0; off >>= 1)
            #pragma unroll
            for (int j = 0; j < 4; ++j)
                #pragma unroll
                for (int r = 0; r < 4; ++r)
                    yp[j][r] += __shfl_xor(yp[j][r], off);

        // phase 3: in-block rank-4 solve (redundant across lanes; G in SGPRs)
        float sv[4][4];
        #pragma unroll
        for (int r = 0; r < 4; ++r) sv[0][r] = yp[0][r];
        #pragma unroll
        for (int r = 0; r < 4; ++r) {
            float t = yp[1][r];
            #pragma unroll
            for (int cc = 0; cc < 4; ++cc) t += Gx[0][r][cc] * sv[0][cc];
            sv[1][r] = t;
        }
        #pragma unroll
        for (int r = 0; r < 4; ++r) {
            float t = yp[2][r];
            #pragma unroll
            for (int cc = 0; cc < 4; ++cc) t += Gx[1][r][cc] * sv[0][cc];
            #pragma unroll
            for (int cc = 0; cc < 4; ++cc) t += Gx[0][r][cc] * sv[1][cc];
            sv[2][r] = t;
        }
        #pragma unroll
        for (int r = 0; r < 4; ++r) {
            float t = yp[3][r];
            #pragma unroll
            for (int cc = 0; cc < 4; ++cc) t += Gx[2][r][cc] * sv[0][cc];
            #pragma unroll
            for (int cc = 0; cc < 4; ++cc) t += Gx[1][r][cc] * sv[1][cc];
            #pragma unroll
            for (int cc = 0; cc < 4; ++cc) t += Gx[0][r][cc] * sv[2][cc];
            sv[3][r] = t;
        }

        // phase 4: reconstruction h_j = g_j + e_j; store if past warm-up
        const bool dostore = (i0 >= warm);
        float e[8];
        #pragma unroll
        for (int d = 0; d < 8; ++d) e[d] = 0.f;
        #pragma unroll
        for (int j = 0; j < 4; ++j) {
            #pragma unroll
            for (int d = 0; d < 8; ++d) {
                const float ps = pk[d].x * sv[j][0] + pk[d].y * sv[j][1]
                               + pk[d].z * sv[j][2] + pk[d].w * sv[j][3];
                e[d] = ak[d] * e[d] + ps;
            }
            if (dostore) {
                float* dd = dst + (size_t)(tstart + i0 + j) * H;
                *(float4*)dd       = (float4){gs[j][0] + e[0], gs[j][1] + e[1],
                                              gs[j][2] + e[2], gs[j][3] + e[3]};
                *(float4*)(dd + 4) = (float4){gs[j][4] + e[4], gs[j][5] + e[5],
                                              gs[j][6] + e[6], gs[j][7] + e[7]};
            }
        }
        // next block's base state: h_4 = g_4 + e_4
        #pragma unroll
        for (int d = 0; d < 8; ++d) g[d] = gs[3][d] + e[d];
    }
}

// ---------------- tier-3 fallback (verified fp32 path) ----------------
__global__ __launch_bounds__(256) void gemm_fused_kernel(
    const float* __restrict__ X, const float* __restrict__ W, float* __restrict__ bx)
{
    __shared__ unsigned short As[BM * LDK];
    __shared__ unsigned short Bs[BN * LDK];
    const int tid  = threadIdx.x;
    const int lane = tid & 63;
    const int wave = tid >> 6;
    const int wm = (wave >> 1) * 64;
    const int wn = (wave & 1) * 64;
    const size_t mbase = (size_t)blockIdx.x * BM;
    const int nbase = blockIdx.y * BN;
    const float* Xb = X + mbase * H;
    const float* Wb = W + (size_t)nbase * H;
    f32x4 acc[4][4];
    #pragma unroll
    for (int i = 0; i < 4; ++i)
        #pragma unroll
        for (int j = 0; j < 4; ++j)
            acc[i][j] = (f32x4){0.f, 0.f, 0.f, 0.f};
    const int r  = lane & 15;
    const int qd = lane >> 4;
    for (int k0 = 0; k0 < H; k0 += BK) {
        #pragma unroll
        for (int i = 0; i < 8; ++i) {
            int idx = tid + i * 256;
            int row = idx >> 4;
            int c4  = (idx & 15) * 4;
            float4 va = *(const float4*)(Xb + (size_t)row * H + k0 + c4);
            float4 vb = *(const float4*)(Wb + (size_t)row * H + k0 + c4);
            ushort4 wa = { f2bf(va.x), f2bf(va.y), f2bf(va.z), f2bf(va.w) };
            ushort4 wb = { f2bf(vb.x), f2bf(vb.y), f2bf(vb.z), f2bf(vb.w) };
            *(ushort4*)&As[row * LDK + c4] = wa;
            *(ushort4*)&Bs[row * LDK + c4] = wb;
        }
        __syncthreads();
        #pragma unroll
        for (int kk = 0; kk < BK; kk += 32) {
            bf16x8 af[4], bfr[4];
            #pragma unroll
            for (int i = 0; i < 4; ++i)
                af[i] = *(const bf16x8*)&As[(wm + i * 16 + r) * LDK + kk + qd * 8];
            #pragma unroll
            for (int j = 0; j < 4; ++j)
                bfr[j] = *(const bf16x8*)&Bs[(wn + j * 16 + r) * LDK + kk + qd * 8];
            #pragma unroll
            for (int i = 0; i < 4; ++i)
                #pragma unroll
                for (int j = 0; j < 4; ++j)
                    acc[i][j] = __builtin_amdgcn_mfma_f32_16x16x32_bf16(
                        af[i], bfr[j], acc[i][j], 0, 0, 0);
        }
        __syncthreads();
    }
    #pragma unroll
    for (int i = 0; i < 4; ++i)
        #pragma unroll
        for (int j = 0; j < 4; ++j)
            #pragma unroll
            for (int e = 0; e < 4; ++e) {
                int m = wm + i * 16 + qd * 4 + e;
                int n = wn + j * 16 + r;
                bx[(mbase + m) * H + nbase + n] = acc[i][j][e];
            }
}

__global__ __launch_bounds__(64) void scan_f32_kernel(
    const float* __restrict__ bx, float* __restrict__ out,
    const float* __restrict__ a_diag, const float* __restrict__ p_vec,
    const float* __restrict__ q_vec)
{
    const int lane = threadIdx.x;
    const int b = blockIdx.y;
    const int d0 = lane * 8;
    float ak[8], hk[8];
    float4 pk[8], qk[8];
    #pragma unroll
    for (int j = 0; j < 8; ++j) {
        ak[j] = a_diag[d0 + j];
        pk[j] = *(const float4*)(p_vec + (d0 + j) * RNK);
        qk[j] = *(const float4*)(q_vec + (d0 + j) * RNK);
        hk[j] = 0.f;
    }
    const float* src = bx + (size_t)b * TT * H + d0;
    float* dst = out + (size_t)b * TT * H + d0;
    for (int i = 0; i < TT; ++i) {
        const float* sp = src + (size_t)i * H;
        float4 va = *(const float4*)sp, vb = *(const float4*)(sp + 4);
        float u[8] = {va.x, va.y, va.z, va.w, vb.x, vb.y, vb.z, vb.w};
        float s0 = 0.f, s1 = 0.f, s2 = 0.f, s3 = 0.f;
        #pragma unroll
        for (int j = 0; j < 8; ++j) {
            s0 += qk[j].x * hk[j]; s1 += qk[j].y * hk[j];
            s2 += qk[j].z * hk[j]; s3 += qk[j].w * hk[j];
        }
        #pragma unroll
        for (int off = 32; off > 0; off >>= 1) {
            s0 += __shfl_xor(s0, off); s1 += __shfl_xor(s1, off);
            s2 += __shfl_xor(s2, off); s3 += __shfl_xor(s3, off);
        }
        #pragma unroll
        for (int j = 0; j < 8; ++j)
            hk[j] = ak[j] * hk[j] + (pk[j].x * s0 + pk[j].y * s1 + pk[j].z * s2 + pk[j].w * s3) + u[j];
        float* d = dst + (size_t)i * H;
        *(float4*)d = (float4){hk[0], hk[1], hk[2], hk[3]};
        *(float4*)(d + 4) = (float4){hk[4], hk[5], hk[6], hk[7]};
    }
}

extern "C" void kernel_launch(void* const* d_in, const int* in_sizes, int n_in,
                              void* d_out, int out_size, void* d_ws, size_t ws_size,
                              hipStream_t stream) {
    (void)in_sizes; (void)n_in; (void)out_size;
    const float* x = (const float*)d_in[0];
    const float* a = (const float*)d_in[1];
    const float* p = (const float*)d_in[2];
    const float* q = (const float*)d_in[3];
    const float* w = (const float*)d_in[4];
    float* out = (float*)d_out;

    const size_t nx    = (size_t)MTOT * H;
    const size_t wbf_b = (size_t)H * H * 2;       // 0.5 MB
    const size_t bxb_b = nx * 2;                  // 67.1 MB (bf16)

    if (d_ws != nullptr && ws_size >= wbf_b + bxb_b) {
        unsigned short* wbf  = (unsigned short*)d_ws;
        unsigned short* bxbf = wbf + (size_t)H * H;
        convert_kernel<<<256, 256, 0, stream>>>(w, wbf, (int)(H * H / 4));
        gemm_x32_kernel<<<(MTOT / BM) * (H / BN), 256, 0, stream>>>(x, wbf, bxbf);
        dim3 g2(NCHUNK, BATCH), b2(64);
        scan_bf_kernel<<<g2, b2, 0, stream>>>(bxbf, out, a, p, q, NCHUNK, JWARM);
    } else {
        // tier 3: fp32 fused GEMM -> d_out, in-place sequential scan (verified safe)
        dim3 g1(MTOT / BM, H / BN), b1(256);
        gemm_fused_kernel<<<g1, b1, 0, stream>>>(x, w, out);
        dim3 g2(1, BATCH), b2(64);
        scan_f32_kernel<<<g2, b2, 0, stream>>>(out, out, a, p, q);
    }
}